// Round 16
// baseline (221.187 us; speedup 1.0000x reference)
//
#include <hip/hip_runtime.h>

#define N_NODES 16384
#define N_EDGES 8192
#define MAXD 32
#define NODE_CAP 64

#define BUILD_BLKS 4096
#define GEMM_BLKS 512
#define PE_BLKS 256
#define CVT_BLKS 320

typedef __attribute__((ext_vector_type(8))) short bf16x8;
typedef __attribute__((ext_vector_type(4))) float f32x4;

// ---- bf16 helpers (RNE) ----
__device__ __forceinline__ unsigned f2b(float f) {
    unsigned u = __float_as_uint(f);
    return (u + 0x7FFFu + ((u >> 16) & 1u)) >> 16;
}
__device__ __forceinline__ unsigned pack2(float lo, float hi) {
    return f2b(lo) | (f2b(hi) << 16);
}
__device__ __forceinline__ float blo(unsigned w) { return __uint_as_float(w << 16); }
__device__ __forceinline__ float bhi(unsigned w) { return __uint_as_float(w & 0xFFFF0000u); }

// ---- one uint4 of a row: ballot-compacted append with wave-level zero skip ----
__device__ __forceinline__ int row_u4(uint4 x, int c4, int row, int base,
                                      int* __restrict__ node_edges, int lane)
{
    unsigned any = x.x | x.y | x.z | x.w;
    if (__ballot(any != 0u) == 0ull) return base;   // ~61% of wave-steps: 1 ballot only
    const unsigned* xs = (const unsigned*)&x;
#pragma unroll
    for (int k2 = 0; k2 < 4; ++k2) {
        unsigned long long m = __ballot(xs[k2] != 0u);
        if (xs[k2]) {
            int pos = base + (int)__popcll(m & ((1ull << lane) - 1ull));
            if (pos < NODE_CAP) node_edges[row * NODE_CAP + pos] = c4 * 4 + k2;
        }
        base += (int)__popcll(m);
    }
    return base;
}

// ---------------- scan: one wave per H row, atomic-free, software-pipelined ----------------
__global__ __launch_bounds__(256, 8) void scan_rows_k(const float* __restrict__ H,
    int* __restrict__ node_cnt, int* __restrict__ node_edges)
{
    const int wid  = threadIdx.x >> 6;
    const int lane = threadIdx.x & 63;
    const int row  = blockIdx.x * 4 + wid;
    const uint4* Hr = (const uint4*)H + (size_t)row * 2048;
    int base = 0;
    uint4 a0, a1, a2, a3, b0, b1, b2, b3;
    a0 = Hr[0 * 64 + lane]; a1 = Hr[1 * 64 + lane];
    a2 = Hr[2 * 64 + lane]; a3 = Hr[3 * 64 + lane];
#pragma unroll 1
    for (int it = 0; it < 32; it += 8) {
        b0 = Hr[(it + 4) * 64 + lane]; b1 = Hr[(it + 5) * 64 + lane];
        b2 = Hr[(it + 6) * 64 + lane]; b3 = Hr[(it + 7) * 64 + lane];
        base = row_u4(a0, (it + 0) * 64 + lane, row, base, node_edges, lane);
        base = row_u4(a1, (it + 1) * 64 + lane, row, base, node_edges, lane);
        base = row_u4(a2, (it + 2) * 64 + lane, row, base, node_edges, lane);
        base = row_u4(a3, (it + 3) * 64 + lane, row, base, node_edges, lane);
        if (it + 8 < 32) {
            a0 = Hr[(it +  8) * 64 + lane]; a1 = Hr[(it +  9) * 64 + lane];
            a2 = Hr[(it + 10) * 64 + lane]; a3 = Hr[(it + 11) * 64 + lane];
        }
        base = row_u4(b0, (it + 4) * 64 + lane, row, base, node_edges, lane);
        base = row_u4(b1, (it + 5) * 64 + lane, row, base, node_edges, lane);
        base = row_u4(b2, (it + 6) * 64 + lane, row, base, node_edges, lane);
        base = row_u4(b3, (it + 7) * 64 + lane, row, base, node_edges, lane);
    }
    if (lane == 0) node_cnt[row] = base;
}

// ---- merged: build edge lists (needs scan) ∥ vsrc GEMM ∥ pe ∥ bf16 weight transposes ----
// build blocks first (4096), then GEMM (512), pe (256), cvt (320)
__global__ __launch_bounds__(256) void build_vwe_k(
    const int* __restrict__ node_cnt, const int* __restrict__ node_edges,
    int* __restrict__ edge_cnt, int* __restrict__ edge_nodes,
    const float* __restrict__ v, const float* __restrict__ Wv,
    const float* __restrict__ ef, const float* __restrict__ We,
    const float* __restrict__ Wo, const float* __restrict__ W1,
    const float* __restrict__ W2,
    float* __restrict__ vsrc, float* __restrict__ pe,
    unsigned short* __restrict__ Wot, unsigned short* __restrict__ W1t,
    unsigned short* __restrict__ W2t)
{
    const int b = blockIdx.x, tid = threadIdx.x;
    if (b < BUILD_BLKS) {
        int idx = b * 256 + tid;                  // [0, N_NODES*NODE_CAP)
        int n = idx >> 6, s = idx & 63;
        if (s < min(node_cnt[n], NODE_CAP)) {
            int e = node_edges[n * NODE_CAP + s];
            int p = atomicAdd(&edge_cnt[e], 1);
            if (p < MAXD) edge_nodes[e * MAXD + p] = n;
        }
    } else if (b < BUILD_BLKS + GEMM_BLKS) {
        const int row0 = (b - BUILD_BLKS) * 32;
        const int r  = tid >> 4;
        const int c0 = (tid & 15) * 8;
        const float4* A4 = (const float4*)v;
        const float4* B4 = (const float4*)Wv;
        float acc[2][8];
#pragma unroll
        for (int i = 0; i < 2; ++i)
#pragma unroll
            for (int j = 0; j < 8; ++j) acc[i][j] = 0.f;
#pragma unroll 4
        for (int k4 = 0; k4 < 32; ++k4) {
            float4 a0 = A4[(size_t)(row0 + r) * 32 + k4];
            float4 a1 = A4[(size_t)(row0 + r + 16) * 32 + k4];
#pragma unroll
            for (int kk = 0; kk < 4; ++kk) {
                int k = k4 * 4 + kk;
                float4 b0 = B4[k * 32 + (c0 >> 2)];
                float4 b1 = B4[k * 32 + (c0 >> 2) + 1];
                float av0 = kk == 0 ? a0.x : kk == 1 ? a0.y : kk == 2 ? a0.z : a0.w;
                float av1 = kk == 0 ? a1.x : kk == 1 ? a1.y : kk == 2 ? a1.z : a1.w;
                acc[0][0] = fmaf(av0, b0.x, acc[0][0]); acc[0][1] = fmaf(av0, b0.y, acc[0][1]);
                acc[0][2] = fmaf(av0, b0.z, acc[0][2]); acc[0][3] = fmaf(av0, b0.w, acc[0][3]);
                acc[0][4] = fmaf(av0, b1.x, acc[0][4]); acc[0][5] = fmaf(av0, b1.y, acc[0][5]);
                acc[0][6] = fmaf(av0, b1.z, acc[0][6]); acc[0][7] = fmaf(av0, b1.w, acc[0][7]);
                acc[1][0] = fmaf(av1, b0.x, acc[1][0]); acc[1][1] = fmaf(av1, b0.y, acc[1][1]);
                acc[1][2] = fmaf(av1, b0.z, acc[1][2]); acc[1][3] = fmaf(av1, b0.w, acc[1][3]);
                acc[1][4] = fmaf(av1, b1.x, acc[1][4]); acc[1][5] = fmaf(av1, b1.y, acc[1][5]);
                acc[1][6] = fmaf(av1, b1.z, acc[1][6]); acc[1][7] = fmaf(av1, b1.w, acc[1][7]);
            }
        }
#pragma unroll
        for (int i = 0; i < 2; ++i) {
            int row = row0 + r + i * 16;
            float4 o0 = {acc[i][0], acc[i][1], acc[i][2], acc[i][3]};
            float4 o1 = {acc[i][4], acc[i][5], acc[i][6], acc[i][7]};
            *(float4*)&vsrc[(size_t)row * 128 + c0]     = o0;
            *(float4*)&vsrc[(size_t)row * 128 + c0 + 4] = o1;
        }
    } else if (b < BUILD_BLKS + GEMM_BLKS + PE_BLKS) {
        int base = (b - BUILD_BLKS - GEMM_BLKS) * 512 + tid;
#pragma unroll
        for (int t = 0; t < 2; ++t) {
            int g = base + t * 256;
            int n = g >> 3, h = g & 7;
            const float4* ef4 = (const float4*)ef + n * 16;
            float p = 0.f;
#pragma unroll
            for (int d4 = 0; d4 < 16; ++d4) {
                float4 x = ef4[d4];
                p += x.x * We[(d4 * 4 + 0) * 8 + h] + x.y * We[(d4 * 4 + 1) * 8 + h]
                   + x.z * We[(d4 * 4 + 2) * 8 + h] + x.w * We[(d4 * 4 + 3) * 8 + h];
            }
            pe[g] = p;
        }
    } else {
        // one-time bf16 transposes: W1t[256][128], W2t[128][256], Wot[128][128]
        int g2 = (b - BUILD_BLKS - GEMM_BLKS - PE_BLKS) * 256 + tid;   // [0, 81920)
        if (g2 < 32768) {
            int n = g2 >> 7, k = g2 & 127;
            W1t[g2] = (unsigned short)f2b(W1[k * 256 + n]);
        } else if (g2 < 65536) {
            int g3 = g2 - 32768;
            int n = g3 >> 8, k = g3 & 255;
            W2t[g3] = (unsigned short)f2b(W2[k * 128 + n]);
        } else {
            int g4 = g2 - 65536;                          // [0, 16384)
            int n = g4 >> 7, k = g4 & 127;
            Wot[g4] = (unsigned short)f2b(Wo[k * 128 + n]);
        }
    }
}

// ---------------- eexp[e,h] = exp(be[h] + sum_j pe[n_j,h])  (4-way ILP) ----------------
__global__ __launch_bounds__(256) void eexp_k(const int* __restrict__ edge_cnt,
    const int* __restrict__ edge_nodes, const float* __restrict__ pe,
    const float* __restrict__ be, float* __restrict__ eexp)
{
    int g = blockIdx.x * 256 + threadIdx.x;   // (e,h)
    int e = g >> 3, h = g & 7;
    int cnt = min(edge_cnt[e], MAXD);
    float s0 = be[h], s1 = 0.f, s2 = 0.f, s3 = 0.f;
    int j = 0;
    for (; j + 4 <= cnt; j += 4) {
        int4 nn = *(const int4*)&edge_nodes[e * MAXD + j];
        s0 += pe[nn.x * 8 + h];
        s1 += pe[nn.y * 8 + h];
        s2 += pe[nn.z * 8 + h];
        s3 += pe[nn.w * 8 + h];
    }
    for (; j < cnt; ++j) s0 += pe[edge_nodes[e * MAXD + j] * 8 + h];
    eexp[g] = __expf((s0 + s1) + (s2 + s3));  // softmax shift-invariant; |s|=O(1) safe
}

// ---- zu_k: z[n,h] = sum eexp; u[n, h*16..+16) = (1/(z+eps)) * vsrc, stored bf16 ----
__global__ __launch_bounds__(256) void zu_k(const int* __restrict__ node_cnt,
    const int* __restrict__ node_edges, const float* __restrict__ eexp,
    const float* __restrict__ vsrc, uint4* __restrict__ u4)
{
    int g = blockIdx.x * 256 + threadIdx.x;   // (n,h)
    int n = g >> 3, h = g & 7;
    int cnt = min(node_cnt[n], NODE_CAP);
    float z0 = 0.f, z1 = 0.f, z2 = 0.f, z3 = 0.f;
    int i = 0;
    for (; i + 4 <= cnt; i += 4) {
        int4 ee = *(const int4*)&node_edges[n * NODE_CAP + i];
        z0 += eexp[ee.x * 8 + h];
        z1 += eexp[ee.y * 8 + h];
        z2 += eexp[ee.z * 8 + h];
        z3 += eexp[ee.w * 8 + h];
    }
    for (; i < cnt; ++i) z0 += eexp[node_edges[n * NODE_CAP + i] * 8 + h];
    float s = 1.0f / (((z0 + z1) + (z2 + z3)) + 1e-10f);

    const float4* v4 = (const float4*)vsrc + (size_t)n * 32 + h * 4;
    float4 x0 = v4[0], x1 = v4[1], x2 = v4[2], x3 = v4[3];
    uint4 w0, w1;
    w0.x = pack2(s * x0.x, s * x0.y); w0.y = pack2(s * x0.z, s * x0.w);
    w0.z = pack2(s * x1.x, s * x1.y); w0.w = pack2(s * x1.z, s * x1.w);
    w1.x = pack2(s * x2.x, s * x2.y); w1.y = pack2(s * x2.z, s * x2.w);
    w1.z = pack2(s * x3.x, s * x3.y); w1.w = pack2(s * x3.z, s * x3.w);
    u4[(size_t)n * 16 + h * 2]     = w0;
    u4[(size_t)n * 16 + h * 2 + 1] = w1;
}

// ---- msg_k (flat, no LDS): msg[e,c] = eexp[e,h] * sum_j u[n_j,c], bf16 out ----
__global__ __launch_bounds__(256) void msg_k(const int* __restrict__ edge_cnt,
    const int* __restrict__ edge_nodes, const float* __restrict__ eexp,
    const uint4* __restrict__ u4, uint4* __restrict__ msg4)
{
    int g = blockIdx.x * 256 + threadIdx.x;   // [0, 131072): (e, c8)
    int e = g >> 4, c8 = g & 15, h = c8 >> 1;
    int cnt = min(edge_cnt[e], MAXD);
    float eh = eexp[e * 8 + h];
    float a[8];
#pragma unroll
    for (int k = 0; k < 8; ++k) a[k] = 0.f;
    int j = 0;
    for (; j + 4 <= cnt; j += 4) {
        int4 nn = *(const int4*)&edge_nodes[e * MAXD + j];
        uint4 w0 = u4[(size_t)nn.x * 16 + c8];
        uint4 w1 = u4[(size_t)nn.y * 16 + c8];
        uint4 w2 = u4[(size_t)nn.z * 16 + c8];
        uint4 w3 = u4[(size_t)nn.w * 16 + c8];
        a[0] += (blo(w0.x) + blo(w1.x)) + (blo(w2.x) + blo(w3.x));
        a[1] += (bhi(w0.x) + bhi(w1.x)) + (bhi(w2.x) + bhi(w3.x));
        a[2] += (blo(w0.y) + blo(w1.y)) + (blo(w2.y) + blo(w3.y));
        a[3] += (bhi(w0.y) + bhi(w1.y)) + (bhi(w2.y) + bhi(w3.y));
        a[4] += (blo(w0.z) + blo(w1.z)) + (blo(w2.z) + blo(w3.z));
        a[5] += (bhi(w0.z) + bhi(w1.z)) + (bhi(w2.z) + bhi(w3.z));
        a[6] += (blo(w0.w) + blo(w1.w)) + (blo(w2.w) + blo(w3.w));
        a[7] += (bhi(w0.w) + bhi(w1.w)) + (bhi(w2.w) + bhi(w3.w));
    }
    for (; j < cnt; ++j) {
        uint4 w = u4[(size_t)edge_nodes[e * MAXD + j] * 16 + c8];
        a[0] += blo(w.x); a[1] += bhi(w.x); a[2] += blo(w.y); a[3] += bhi(w.y);
        a[4] += blo(w.z); a[5] += bhi(w.z); a[6] += blo(w.w); a[7] += bhi(w.w);
    }
    uint4 w;
    w.x = pack2(a[0] * eh, a[1] * eh); w.y = pack2(a[2] * eh, a[3] * eh);
    w.z = pack2(a[4] * eh, a[5] * eh); w.w = pack2(a[6] * eh, a[7] * eh);
    msg4[g] = w;
}

// ---- final fused (3x MFMA): rst = sum msg ; h = rst@Wo + q ; out = h + relu(h@W1+b1)@W2 + b2 ----
__global__ __launch_bounds__(256) void ffn_agg_k(const float* __restrict__ q,
    const int* __restrict__ node_cnt, const int* __restrict__ node_edges,
    const uint4* __restrict__ msg4, const unsigned short* __restrict__ Wot,
    const unsigned short* __restrict__ W1t, const float* __restrict__ b1,
    const unsigned short* __restrict__ W2t, const float* __restrict__ b2,
    float* __restrict__ out)
{
    __shared__ unsigned short Ra[32][128];
    __shared__ float Hs[32][128];
    __shared__ unsigned short Ha[32][128];
    __shared__ unsigned short Ta[32][256];

    const int tid  = threadIdx.x;
    const int row0 = blockIdx.x * 32;

    {   // aggregate: rst = sum msg (bf16 gathers, 2-edge ILP); store bf16 into Ra
        int r = tid >> 3, lc = tid & 7;
        int n = row0 + r;
        float a[16];
#pragma unroll
        for (int k = 0; k < 16; ++k) a[k] = 0.f;
        int cnt = min(node_cnt[n], NODE_CAP);
        int i = 0;
        for (; i + 2 <= cnt; i += 2) {
            int ea = node_edges[n * NODE_CAP + i];
            int eb = node_edges[n * NODE_CAP + i + 1];
            uint4 wa0 = msg4[(size_t)ea * 16 + lc * 2];
            uint4 wa1 = msg4[(size_t)ea * 16 + lc * 2 + 1];
            uint4 wb0 = msg4[(size_t)eb * 16 + lc * 2];
            uint4 wb1 = msg4[(size_t)eb * 16 + lc * 2 + 1];
            a[0]  += blo(wa0.x) + blo(wb0.x); a[1]  += bhi(wa0.x) + bhi(wb0.x);
            a[2]  += blo(wa0.y) + blo(wb0.y); a[3]  += bhi(wa0.y) + bhi(wb0.y);
            a[4]  += blo(wa0.z) + blo(wb0.z); a[5]  += bhi(wa0.z) + bhi(wb0.z);
            a[6]  += blo(wa0.w) + blo(wb0.w); a[7]  += bhi(wa0.w) + bhi(wb0.w);
            a[8]  += blo(wa1.x) + blo(wb1.x); a[9]  += bhi(wa1.x) + bhi(wb1.x);
            a[10] += blo(wa1.y) + blo(wb1.y); a[11] += bhi(wa1.y) + bhi(wb1.y);
            a[12] += blo(wa1.z) + blo(wb1.z); a[13] += bhi(wa1.z) + bhi(wb1.z);
            a[14] += blo(wa1.w) + blo(wb1.w); a[15] += bhi(wa1.w) + bhi(wb1.w);
        }
        for (; i < cnt; ++i) {
            int e = node_edges[n * NODE_CAP + i];
            uint4 w0 = msg4[(size_t)e * 16 + lc * 2];
            uint4 w1 = msg4[(size_t)e * 16 + lc * 2 + 1];
            a[0]  += blo(w0.x); a[1]  += bhi(w0.x); a[2]  += blo(w0.y); a[3]  += bhi(w0.y);
            a[4]  += blo(w0.z); a[5]  += bhi(w0.z); a[6]  += blo(w0.w); a[7]  += bhi(w0.w);
            a[8]  += blo(w1.x); a[9]  += bhi(w1.x); a[10] += blo(w1.y); a[11] += bhi(w1.y);
            a[12] += blo(w1.z); a[13] += bhi(w1.z); a[14] += blo(w1.w); a[15] += bhi(w1.w);
        }
#pragma unroll
        for (int t = 0; t < 8; ++t)
            *(unsigned*)&Ra[r][lc * 16 + 2 * t] = pack2(a[2*t], a[2*t+1]);
    }
    __syncthreads();

    const int wid  = tid >> 6;
    const int lane = tid & 63;
    const int lm = lane & 15;
    const int lk = (lane >> 4) * 8;
    const int lr = (lane >> 4) * 4;
    const int m  = wid & 1;

    // ---- phase 0 (MFMA): h = rst @ Wo + q ----
    {
        const int ng0 = (wid >> 1) * 4;
        f32x4 acc[4];
#pragma unroll
        for (int nt = 0; nt < 4; ++nt) acc[nt] = (f32x4){0.f, 0.f, 0.f, 0.f};
#pragma unroll
        for (int kt = 0; kt < 4; ++kt) {
            bf16x8 av = *(const bf16x8*)&Ra[m * 16 + lm][kt * 32 + lk];
#pragma unroll
            for (int nt = 0; nt < 4; ++nt) {
                bf16x8 bv = *(const bf16x8*)&Wot[(size_t)((ng0 + nt) * 16 + lm) * 128
                                                 + kt * 32 + lk];
                acc[nt] = __builtin_amdgcn_mfma_f32_16x16x32_bf16(av, bv, acc[nt], 0, 0, 0);
            }
        }
#pragma unroll
        for (int nt = 0; nt < 4; ++nt) {
            int col = (ng0 + nt) * 16 + lm;
#pragma unroll
            for (int j = 0; j < 4; ++j) {
                int rl = m * 16 + lr + j;
                float hv = acc[nt][j] + q[(size_t)(row0 + rl) * 128 + col];
                Hs[rl][col] = hv;
                Ha[rl][col] = (unsigned short)f2b(hv);
            }
        }
    }
    __syncthreads();

    // ---- phase A (MFMA): T = relu(h @ W1 + b1) ----
    {
        const int ng0 = (wid >> 1) * 8;
        f32x4 acc[8];
#pragma unroll
        for (int nt = 0; nt < 8; ++nt) acc[nt] = (f32x4){0.f, 0.f, 0.f, 0.f};
#pragma unroll
        for (int kt = 0; kt < 4; ++kt) {
            bf16x8 av = *(const bf16x8*)&Ha[m * 16 + lm][kt * 32 + lk];
#pragma unroll
            for (int nt = 0; nt < 8; ++nt) {
                bf16x8 bv = *(const bf16x8*)&W1t[(size_t)((ng0 + nt) * 16 + lm) * 128
                                                 + kt * 32 + lk];
                acc[nt] = __builtin_amdgcn_mfma_f32_16x16x32_bf16(av, bv, acc[nt], 0, 0, 0);
            }
        }
#pragma unroll
        for (int nt = 0; nt < 8; ++nt) {
            int col = (ng0 + nt) * 16 + lm;
            float bb = b1[col];
#pragma unroll
            for (int j = 0; j < 4; ++j) {
                float t = fmaxf(acc[nt][j] + bb, 0.f);
                Ta[m * 16 + lr + j][col] = (unsigned short)f2b(t);
            }
        }
    }
    __syncthreads();

    // ---- phase B (MFMA): out = Hs + T @ W2 + b2 ----
    {
        const int ng0 = (wid >> 1) * 4;
        f32x4 acc[4];
#pragma unroll
        for (int nt = 0; nt < 4; ++nt) acc[nt] = (f32x4){0.f, 0.f, 0.f, 0.f};
#pragma unroll
        for (int kt = 0; kt < 8; ++kt) {
            bf16x8 av = *(const bf16x8*)&Ta[m * 16 + lm][kt * 32 + lk];
#pragma unroll
            for (int nt = 0; nt < 4; ++nt) {
                bf16x8 bv = *(const bf16x8*)&W2t[(size_t)((ng0 + nt) * 16 + lm) * 256
                                                 + kt * 32 + lk];
                acc[nt] = __builtin_amdgcn_mfma_f32_16x16x32_bf16(av, bv, acc[nt], 0, 0, 0);
            }
        }
#pragma unroll
        for (int nt = 0; nt < 4; ++nt) {
            int col = (ng0 + nt) * 16 + lm;
            float bb = b2[col];
#pragma unroll
            for (int j = 0; j < 4; ++j) {
                int rl = m * 16 + lr + j;
                out[(size_t)(row0 + rl) * 128 + col] = Hs[rl][col] + acc[nt][j] + bb;
            }
        }
    }
}

extern "C" void kernel_launch(void* const* d_in, const int* in_sizes, int n_in,
                              void* d_out, int out_size, void* d_ws, size_t ws_size,
                              hipStream_t stream)
{
    const float* q  = (const float*)d_in[0];
    // d_in[1] = k : dead (per-node q·k dot is segment-constant, cancels in softmax)
    const float* v  = (const float*)d_in[2];
    const float* ef = (const float*)d_in[3];
    const float* H  = (const float*)d_in[4];
    // d_in[5] = Wq, d_in[6] = Wk : dead
    const float* Wv = (const float*)d_in[7];
    const float* We = (const float*)d_in[8];
    const float* be = (const float*)d_in[9];
    const float* Wo = (const float*)d_in[10];
    const float* W1 = (const float*)d_in[11];
    const float* b1 = (const float*)d_in[12];
    const float* W2 = (const float*)d_in[13];
    const float* b2 = (const float*)d_in[14];
    float* out = (float*)d_out;

    char* w = (char*)d_ws;
    auto carve = [&](size_t bytes) -> void* {
        void* p = (void*)w;
        w += (bytes + 255) & ~(size_t)255;
        return p;
    };
    int* edge_cnt   = (int*)carve(N_EDGES * 4);                    // zeroed (32 KB only)
    size_t zero_bytes = (size_t)(w - (char*)d_ws);
    int* node_cnt   = (int*)carve(N_NODES * 4);                    // plain-written by scan
    int* edge_nodes = (int*)carve((size_t)N_EDGES * MAXD * 4);
    int* node_edges = (int*)carve((size_t)N_NODES * NODE_CAP * 4);
    float* pe       = (float*)carve((size_t)N_NODES * 8 * 4);
    float* eexp     = (float*)carve((size_t)N_EDGES * 8 * 4);
    float* vsrc     = (float*)carve((size_t)N_NODES * 128 * 4);
    uint4* u4       = (uint4*)carve((size_t)N_NODES * 128 * 2);    // bf16
    uint4* msg4     = (uint4*)carve((size_t)N_EDGES * 128 * 2);    // bf16
    unsigned short* W1t = (unsigned short*)carve(32768 * 2);       // bf16 W1^T [256][128]
    unsigned short* W2t = (unsigned short*)carve(32768 * 2);       // bf16 W2^T [128][256]
    unsigned short* Wot = (unsigned short*)carve(16384 * 2);       // bf16 Wo^T [128][128]
    (void)ws_size; (void)in_sizes; (void)n_in; (void)out_size;

    hipMemsetAsync(d_ws, 0, zero_bytes, stream);

    scan_rows_k<<<N_NODES / 4, 256, 0, stream>>>(H, node_cnt, node_edges);
    build_vwe_k<<<BUILD_BLKS + GEMM_BLKS + PE_BLKS + CVT_BLKS, 256, 0, stream>>>(
        node_cnt, node_edges, edge_cnt, edge_nodes,
        v, Wv, ef, We, Wo, W1, W2, vsrc, pe, Wot, W1t, W2t);
    eexp_k<<<(N_EDGES * 8) / 256, 256, 0, stream>>>(edge_cnt, edge_nodes, pe, be, eexp);
    zu_k<<<(N_NODES * 8) / 256, 256, 0, stream>>>(node_cnt, node_edges, eexp, vsrc, u4);
    msg_k<<<(N_EDGES * 16) / 256, 256, 0, stream>>>(edge_cnt, edge_nodes, eexp, u4, msg4);
    ffn_agg_k<<<N_NODES / 32, 256, 0, stream>>>(q, node_cnt, node_edges, msg4,
                                                Wot, W1t, b1, W2t, b2, out);
}

// Round 17
// 207.819 us; speedup vs baseline: 1.0643x; 1.0643x over previous
//
#include <hip/hip_runtime.h>

#define N_NODES 16384
#define N_EDGES 8192
#define MAXD 32
#define NODE_CAP 64

#define GEMM_BLKS 512
#define PE_BLKS 256
#define CVT_BLKS 320

typedef __attribute__((ext_vector_type(8))) short bf16x8;
typedef __attribute__((ext_vector_type(4))) float f32x4;

// ---- bf16 helpers (RNE) ----
__device__ __forceinline__ unsigned f2b(float f) {
    unsigned u = __float_as_uint(f);
    return (u + 0x7FFFu + ((u >> 16) & 1u)) >> 16;
}
__device__ __forceinline__ unsigned pack2(float lo, float hi) {
    return f2b(lo) | (f2b(hi) << 16);
}
__device__ __forceinline__ float blo(unsigned w) { return __uint_as_float(w << 16); }
__device__ __forceinline__ float bhi(unsigned w) { return __uint_as_float(w & 0xFFFF0000u); }

// ---- process one uint4 of a row: ballot-compacted node_edges append, NO atomics ----
__device__ __forceinline__ int row_u4(uint4 x, int c4, int row, int base,
                                      int* __restrict__ node_edges, int lane)
{
    const unsigned* xs = (const unsigned*)&x;
#pragma unroll
    for (int k2 = 0; k2 < 4; ++k2) {
        unsigned long long m = __ballot(xs[k2] != 0u);
        if (xs[k2]) {
            int pos = base + (int)__popcll(m & ((1ull << lane) - 1ull));
            if (pos < NODE_CAP) node_edges[row * NODE_CAP + pos] = c4 * 4 + k2;
        }
        base += (int)__popcll(m);
    }
    return base;
}

// ---------------- scan: one wave per H row, atomic-free, software-pipelined ----------------
// loads for batch i+1 issued BEFORE processing batch i -> 4-8 loads always in flight
__global__ __launch_bounds__(256, 8) void scan_rows_k(const float* __restrict__ H,
    int* __restrict__ node_cnt, int* __restrict__ node_edges)
{
    const int wid  = threadIdx.x >> 6;
    const int lane = threadIdx.x & 63;
    const int row  = blockIdx.x * 4 + wid;
    const uint4* Hr = (const uint4*)H + (size_t)row * 2048;
    int base = 0;
    uint4 a0, a1, a2, a3, b0, b1, b2, b3;
    a0 = Hr[0 * 64 + lane]; a1 = Hr[1 * 64 + lane];
    a2 = Hr[2 * 64 + lane]; a3 = Hr[3 * 64 + lane];
#pragma unroll 1
    for (int it = 0; it < 32; it += 8) {
        b0 = Hr[(it + 4) * 64 + lane]; b1 = Hr[(it + 5) * 64 + lane];
        b2 = Hr[(it + 6) * 64 + lane]; b3 = Hr[(it + 7) * 64 + lane];
        base = row_u4(a0, (it + 0) * 64 + lane, row, base, node_edges, lane);
        base = row_u4(a1, (it + 1) * 64 + lane, row, base, node_edges, lane);
        base = row_u4(a2, (it + 2) * 64 + lane, row, base, node_edges, lane);
        base = row_u4(a3, (it + 3) * 64 + lane, row, base, node_edges, lane);
        if (it + 8 < 32) {
            a0 = Hr[(it +  8) * 64 + lane]; a1 = Hr[(it +  9) * 64 + lane];
            a2 = Hr[(it + 10) * 64 + lane]; a3 = Hr[(it + 11) * 64 + lane];
        }
        base = row_u4(b0, (it + 4) * 64 + lane, row, base, node_edges, lane);
        base = row_u4(b1, (it + 5) * 64 + lane, row, base, node_edges, lane);
        base = row_u4(b2, (it + 6) * 64 + lane, row, base, node_edges, lane);
        base = row_u4(b3, (it + 7) * 64 + lane, row, base, node_edges, lane);
    }
    if (lane == 0) node_cnt[row] = base;
}

// ---------------- build edge lists from node lists (high-TLP atomic pass) ----------------
__global__ __launch_bounds__(256) void build_k(const int* __restrict__ node_cnt,
    const int* __restrict__ node_edges, int* __restrict__ edge_cnt,
    int* __restrict__ edge_nodes)
{
    int idx = blockIdx.x * 256 + threadIdx.x;     // [0, N_NODES*NODE_CAP)
    int n = idx >> 6, s = idx & 63;
    if (s < min(node_cnt[n], NODE_CAP)) {
        int e = node_edges[n * NODE_CAP + s];
        int p = atomicAdd(&edge_cnt[e], 1);
        if (p < MAXD) edge_nodes[e * MAXD + p] = n;
    }
}

// ---- vwe_k: vsrc = v @ Wv ∥ pe = ef @ We ∥ one-time bf16 transpose of Wo/W1/W2 ----
__global__ __launch_bounds__(256) void vwe_k(
    const float* __restrict__ v, const float* __restrict__ Wv,
    const float* __restrict__ ef, const float* __restrict__ We,
    const float* __restrict__ Wo, const float* __restrict__ W1,
    const float* __restrict__ W2,
    float* __restrict__ vsrc, float* __restrict__ pe,
    unsigned short* __restrict__ Wot, unsigned short* __restrict__ W1t,
    unsigned short* __restrict__ W2t)
{
    const int b = blockIdx.x, tid = threadIdx.x;
    if (b < GEMM_BLKS) {
        const int row0 = b * 32;
        const int r  = tid >> 4;
        const int c0 = (tid & 15) * 8;
        const float4* A4 = (const float4*)v;
        const float4* B4 = (const float4*)Wv;
        float acc[2][8];
#pragma unroll
        for (int i = 0; i < 2; ++i)
#pragma unroll
            for (int j = 0; j < 8; ++j) acc[i][j] = 0.f;
#pragma unroll 4
        for (int k4 = 0; k4 < 32; ++k4) {
            float4 a0 = A4[(size_t)(row0 + r) * 32 + k4];
            float4 a1 = A4[(size_t)(row0 + r + 16) * 32 + k4];
#pragma unroll
            for (int kk = 0; kk < 4; ++kk) {
                int k = k4 * 4 + kk;
                float4 b0 = B4[k * 32 + (c0 >> 2)];
                float4 b1 = B4[k * 32 + (c0 >> 2) + 1];
                float av0 = kk == 0 ? a0.x : kk == 1 ? a0.y : kk == 2 ? a0.z : a0.w;
                float av1 = kk == 0 ? a1.x : kk == 1 ? a1.y : kk == 2 ? a1.z : a1.w;
                acc[0][0] = fmaf(av0, b0.x, acc[0][0]); acc[0][1] = fmaf(av0, b0.y, acc[0][1]);
                acc[0][2] = fmaf(av0, b0.z, acc[0][2]); acc[0][3] = fmaf(av0, b0.w, acc[0][3]);
                acc[0][4] = fmaf(av0, b1.x, acc[0][4]); acc[0][5] = fmaf(av0, b1.y, acc[0][5]);
                acc[0][6] = fmaf(av0, b1.z, acc[0][6]); acc[0][7] = fmaf(av0, b1.w, acc[0][7]);
                acc[1][0] = fmaf(av1, b0.x, acc[1][0]); acc[1][1] = fmaf(av1, b0.y, acc[1][1]);
                acc[1][2] = fmaf(av1, b0.z, acc[1][2]); acc[1][3] = fmaf(av1, b0.w, acc[1][3]);
                acc[1][4] = fmaf(av1, b1.x, acc[1][4]); acc[1][5] = fmaf(av1, b1.y, acc[1][5]);
                acc[1][6] = fmaf(av1, b1.z, acc[1][6]); acc[1][7] = fmaf(av1, b1.w, acc[1][7]);
            }
        }
#pragma unroll
        for (int i = 0; i < 2; ++i) {
            int row = row0 + r + i * 16;
            float4 o0 = {acc[i][0], acc[i][1], acc[i][2], acc[i][3]};
            float4 o1 = {acc[i][4], acc[i][5], acc[i][6], acc[i][7]};
            *(float4*)&vsrc[(size_t)row * 128 + c0]     = o0;
            *(float4*)&vsrc[(size_t)row * 128 + c0 + 4] = o1;
        }
    } else if (b < GEMM_BLKS + PE_BLKS) {
        int base = (b - GEMM_BLKS) * 512 + tid;
#pragma unroll
        for (int t = 0; t < 2; ++t) {
            int g = base + t * 256;
            int n = g >> 3, h = g & 7;
            const float4* ef4 = (const float4*)ef + n * 16;
            float p = 0.f;
#pragma unroll
            for (int d4 = 0; d4 < 16; ++d4) {
                float4 x = ef4[d4];
                p += x.x * We[(d4 * 4 + 0) * 8 + h] + x.y * We[(d4 * 4 + 1) * 8 + h]
                   + x.z * We[(d4 * 4 + 2) * 8 + h] + x.w * We[(d4 * 4 + 3) * 8 + h];
            }
            pe[g] = p;
        }
    } else {
        // one-time bf16 transposes: W1t[256][128], W2t[128][256], Wot[128][128]
        int g2 = (b - GEMM_BLKS - PE_BLKS) * 256 + tid;   // [0, 81920)
        if (g2 < 32768) {
            int n = g2 >> 7, k = g2 & 127;
            W1t[g2] = (unsigned short)f2b(W1[k * 256 + n]);
        } else if (g2 < 65536) {
            int g3 = g2 - 32768;
            int n = g3 >> 8, k = g3 & 255;
            W2t[g3] = (unsigned short)f2b(W2[k * 128 + n]);
        } else {
            int g4 = g2 - 65536;                          // [0, 16384)
            int n = g4 >> 7, k = g4 & 127;
            Wot[g4] = (unsigned short)f2b(Wo[k * 128 + n]);
        }
    }
}

// ---------------- eexp[e,h] = exp(be[h] + sum_j pe[n_j,h])  (4-way ILP) ----------------
__global__ __launch_bounds__(256) void eexp_k(const int* __restrict__ edge_cnt,
    const int* __restrict__ edge_nodes, const float* __restrict__ pe,
    const float* __restrict__ be, float* __restrict__ eexp)
{
    int g = blockIdx.x * 256 + threadIdx.x;   // (e,h)
    int e = g >> 3, h = g & 7;
    int cnt = min(edge_cnt[e], MAXD);
    float s0 = be[h], s1 = 0.f, s2 = 0.f, s3 = 0.f;
    int j = 0;
    for (; j + 4 <= cnt; j += 4) {
        int4 nn = *(const int4*)&edge_nodes[e * MAXD + j];
        s0 += pe[nn.x * 8 + h];
        s1 += pe[nn.y * 8 + h];
        s2 += pe[nn.z * 8 + h];
        s3 += pe[nn.w * 8 + h];
    }
    for (; j < cnt; ++j) s0 += pe[edge_nodes[e * MAXD + j] * 8 + h];
    eexp[g] = __expf((s0 + s1) + (s2 + s3));  // softmax shift-invariant; |s|=O(1) safe
}

// ---- zu_k: z[n,h] = sum eexp; u[n, h*16..+16) = (1/(z+eps)) * vsrc, stored bf16 ----
__global__ __launch_bounds__(256) void zu_k(const int* __restrict__ node_cnt,
    const int* __restrict__ node_edges, const float* __restrict__ eexp,
    const float* __restrict__ vsrc, uint4* __restrict__ u4)
{
    int g = blockIdx.x * 256 + threadIdx.x;   // (n,h)
    int n = g >> 3, h = g & 7;
    int cnt = min(node_cnt[n], NODE_CAP);
    float z0 = 0.f, z1 = 0.f, z2 = 0.f, z3 = 0.f;
    int i = 0;
    for (; i + 4 <= cnt; i += 4) {
        int4 ee = *(const int4*)&node_edges[n * NODE_CAP + i];
        z0 += eexp[ee.x * 8 + h];
        z1 += eexp[ee.y * 8 + h];
        z2 += eexp[ee.z * 8 + h];
        z3 += eexp[ee.w * 8 + h];
    }
    for (; i < cnt; ++i) z0 += eexp[node_edges[n * NODE_CAP + i] * 8 + h];
    float s = 1.0f / (((z0 + z1) + (z2 + z3)) + 1e-10f);

    const float4* v4 = (const float4*)vsrc + (size_t)n * 32 + h * 4;
    float4 x0 = v4[0], x1 = v4[1], x2 = v4[2], x3 = v4[3];
    uint4 w0, w1;
    w0.x = pack2(s * x0.x, s * x0.y); w0.y = pack2(s * x0.z, s * x0.w);
    w0.z = pack2(s * x1.x, s * x1.y); w0.w = pack2(s * x1.z, s * x1.w);
    w1.x = pack2(s * x2.x, s * x2.y); w1.y = pack2(s * x2.z, s * x2.w);
    w1.z = pack2(s * x3.x, s * x3.y); w1.w = pack2(s * x3.z, s * x3.w);
    u4[(size_t)n * 16 + h * 2]     = w0;
    u4[(size_t)n * 16 + h * 2 + 1] = w1;
}

// ---- msg_k (flat, no LDS): msg[e,c] = eexp[e,h] * sum_j u[n_j,c], bf16 out ----
__global__ __launch_bounds__(256) void msg_k(const int* __restrict__ edge_cnt,
    const int* __restrict__ edge_nodes, const float* __restrict__ eexp,
    const uint4* __restrict__ u4, uint4* __restrict__ msg4)
{
    int g = blockIdx.x * 256 + threadIdx.x;   // [0, 131072): (e, c8)
    int e = g >> 4, c8 = g & 15, h = c8 >> 1;
    int cnt = min(edge_cnt[e], MAXD);
    float eh = eexp[e * 8 + h];
    float a[8];
#pragma unroll
    for (int k = 0; k < 8; ++k) a[k] = 0.f;
    int j = 0;
    for (; j + 4 <= cnt; j += 4) {
        int4 nn = *(const int4*)&edge_nodes[e * MAXD + j];
        uint4 w0 = u4[(size_t)nn.x * 16 + c8];
        uint4 w1 = u4[(size_t)nn.y * 16 + c8];
        uint4 w2 = u4[(size_t)nn.z * 16 + c8];
        uint4 w3 = u4[(size_t)nn.w * 16 + c8];
        a[0] += (blo(w0.x) + blo(w1.x)) + (blo(w2.x) + blo(w3.x));
        a[1] += (bhi(w0.x) + bhi(w1.x)) + (bhi(w2.x) + bhi(w3.x));
        a[2] += (blo(w0.y) + blo(w1.y)) + (blo(w2.y) + blo(w3.y));
        a[3] += (bhi(w0.y) + bhi(w1.y)) + (bhi(w2.y) + bhi(w3.y));
        a[4] += (blo(w0.z) + blo(w1.z)) + (blo(w2.z) + blo(w3.z));
        a[5] += (bhi(w0.z) + bhi(w1.z)) + (bhi(w2.z) + bhi(w3.z));
        a[6] += (blo(w0.w) + blo(w1.w)) + (blo(w2.w) + blo(w3.w));
        a[7] += (bhi(w0.w) + bhi(w1.w)) + (bhi(w2.w) + bhi(w3.w));
    }
    for (; j < cnt; ++j) {
        uint4 w = u4[(size_t)edge_nodes[e * MAXD + j] * 16 + c8];
        a[0] += blo(w.x); a[1] += bhi(w.x); a[2] += blo(w.y); a[3] += bhi(w.y);
        a[4] += blo(w.z); a[5] += bhi(w.z); a[6] += blo(w.w); a[7] += bhi(w.w);
    }
    uint4 w;
    w.x = pack2(a[0] * eh, a[1] * eh); w.y = pack2(a[2] * eh, a[3] * eh);
    w.z = pack2(a[4] * eh, a[5] * eh); w.w = pack2(a[6] * eh, a[7] * eh);
    msg4[g] = w;
}

// ---- final fused (3x MFMA): rst = sum msg ; h = rst@Wo + q ; out = h + relu(h@W1+b1)@W2 + b2 ----
// LDS: Ra 8K + Hs 16K + Ha 8K + Ta 16K = 48K -> 3 blocks/CU
__global__ __launch_bounds__(256) void ffn_agg_k(const float* __restrict__ q,
    const int* __restrict__ node_cnt, const int* __restrict__ node_edges,
    const uint4* __restrict__ msg4, const unsigned short* __restrict__ Wot,
    const unsigned short* __restrict__ W1t, const float* __restrict__ b1,
    const unsigned short* __restrict__ W2t, const float* __restrict__ b2,
    float* __restrict__ out)
{
    __shared__ unsigned short Ra[32][128];     // bf16 rst (phase-0 A operand)
    __shared__ float Hs[32][128];              // f32 h (residual source)
    __shared__ unsigned short Ha[32][128];     // bf16 h (phase-A A operand)
    __shared__ unsigned short Ta[32][256];     // bf16 T (phase-B A operand)

    const int tid  = threadIdx.x;
    const int row0 = blockIdx.x * 32;

    {   // aggregate: rst = sum msg (bf16 gathers, 2-edge ILP); store bf16 into Ra
        int r = tid >> 3, lc = tid & 7;        // 16 channels: [lc*16, lc*16+16)
        int n = row0 + r;
        float a[16];
#pragma unroll
        for (int k = 0; k < 16; ++k) a[k] = 0.f;
        int cnt = min(node_cnt[n], NODE_CAP);
        int i = 0;
        for (; i + 2 <= cnt; i += 2) {
            int ea = node_edges[n * NODE_CAP + i];
            int eb = node_edges[n * NODE_CAP + i + 1];
            uint4 wa0 = msg4[(size_t)ea * 16 + lc * 2];
            uint4 wa1 = msg4[(size_t)ea * 16 + lc * 2 + 1];
            uint4 wb0 = msg4[(size_t)eb * 16 + lc * 2];
            uint4 wb1 = msg4[(size_t)eb * 16 + lc * 2 + 1];
            a[0]  += blo(wa0.x) + blo(wb0.x); a[1]  += bhi(wa0.x) + bhi(wb0.x);
            a[2]  += blo(wa0.y) + blo(wb0.y); a[3]  += bhi(wa0.y) + bhi(wb0.y);
            a[4]  += blo(wa0.z) + blo(wb0.z); a[5]  += bhi(wa0.z) + bhi(wb0.z);
            a[6]  += blo(wa0.w) + blo(wb0.w); a[7]  += bhi(wa0.w) + bhi(wb0.w);
            a[8]  += blo(wa1.x) + blo(wb1.x); a[9]  += bhi(wa1.x) + bhi(wb1.x);
            a[10] += blo(wa1.y) + blo(wb1.y); a[11] += bhi(wa1.y) + bhi(wb1.y);
            a[12] += blo(wa1.z) + blo(wb1.z); a[13] += bhi(wa1.z) + bhi(wb1.z);
            a[14] += blo(wa1.w) + blo(wb1.w); a[15] += bhi(wa1.w) + bhi(wb1.w);
        }
        for (; i < cnt; ++i) {
            int e = node_edges[n * NODE_CAP + i];
            uint4 w0 = msg4[(size_t)e * 16 + lc * 2];
            uint4 w1 = msg4[(size_t)e * 16 + lc * 2 + 1];
            a[0]  += blo(w0.x); a[1]  += bhi(w0.x); a[2]  += blo(w0.y); a[3]  += bhi(w0.y);
            a[4]  += blo(w0.z); a[5]  += bhi(w0.z); a[6]  += blo(w0.w); a[7]  += bhi(w0.w);
            a[8]  += blo(w1.x); a[9]  += bhi(w1.x); a[10] += blo(w1.y); a[11] += bhi(w1.y);
            a[12] += blo(w1.z); a[13] += bhi(w1.z); a[14] += blo(w1.w); a[15] += bhi(w1.w);
        }
#pragma unroll
        for (int t = 0; t < 8; ++t)
            *(unsigned*)&Ra[r][lc * 16 + 2 * t] = pack2(a[2*t], a[2*t+1]);
    }
    __syncthreads();

    const int wid  = tid >> 6;
    const int lane = tid & 63;
    const int lm = lane & 15;
    const int lk = (lane >> 4) * 8;
    const int lr = (lane >> 4) * 4;
    const int m  = wid & 1;

    // ---- phase 0 (MFMA): h = rst @ Wo + q ----
    {
        const int ng0 = (wid >> 1) * 4;
        f32x4 acc[4];
#pragma unroll
        for (int nt = 0; nt < 4; ++nt) acc[nt] = (f32x4){0.f, 0.f, 0.f, 0.f};
#pragma unroll
        for (int kt = 0; kt < 4; ++kt) {
            bf16x8 av = *(const bf16x8*)&Ra[m * 16 + lm][kt * 32 + lk];
#pragma unroll
            for (int nt = 0; nt < 4; ++nt) {
                bf16x8 bv = *(const bf16x8*)&Wot[(size_t)((ng0 + nt) * 16 + lm) * 128
                                                 + kt * 32 + lk];
                acc[nt] = __builtin_amdgcn_mfma_f32_16x16x32_bf16(av, bv, acc[nt], 0, 0, 0);
            }
        }
#pragma unroll
        for (int nt = 0; nt < 4; ++nt) {
            int col = (ng0 + nt) * 16 + lm;
#pragma unroll
            for (int j = 0; j < 4; ++j) {
                int rl = m * 16 + lr + j;
                float hv = acc[nt][j] + q[(size_t)(row0 + rl) * 128 + col];
                Hs[rl][col] = hv;
                Ha[rl][col] = (unsigned short)f2b(hv);
            }
        }
    }
    __syncthreads();

    // ---- phase A (MFMA): T = relu(h @ W1 + b1) ----
    {
        const int ng0 = (wid >> 1) * 8;
        f32x4 acc[8];
#pragma unroll
        for (int nt = 0; nt < 8; ++nt) acc[nt] = (f32x4){0.f, 0.f, 0.f, 0.f};
#pragma unroll
        for (int kt = 0; kt < 4; ++kt) {
            bf16x8 av = *(const bf16x8*)&Ha[m * 16 + lm][kt * 32 + lk];
#pragma unroll
            for (int nt = 0; nt < 8; ++nt) {
                bf16x8 bv = *(const bf16x8*)&W1t[(size_t)((ng0 + nt) * 16 + lm) * 128
                                                 + kt * 32 + lk];
                acc[nt] = __builtin_amdgcn_mfma_f32_16x16x32_bf16(av, bv, acc[nt], 0, 0, 0);
            }
        }
#pragma unroll
        for (int nt = 0; nt < 8; ++nt) {
            int col = (ng0 + nt) * 16 + lm;
            float bb = b1[col];
#pragma unroll
            for (int j = 0; j < 4; ++j) {
                float t = fmaxf(acc[nt][j] + bb, 0.f);
                Ta[m * 16 + lr + j][col] = (unsigned short)f2b(t);
            }
        }
    }
    __syncthreads();

    // ---- phase B (MFMA): out = Hs + T @ W2 + b2 ----
    {
        const int ng0 = (wid >> 1) * 4;
        f32x4 acc[4];
#pragma unroll
        for (int nt = 0; nt < 4; ++nt) acc[nt] = (f32x4){0.f, 0.f, 0.f, 0.f};
#pragma unroll
        for (int kt = 0; kt < 8; ++kt) {
            bf16x8 av = *(const bf16x8*)&Ta[m * 16 + lm][kt * 32 + lk];
#pragma unroll
            for (int nt = 0; nt < 4; ++nt) {
                bf16x8 bv = *(const bf16x8*)&W2t[(size_t)((ng0 + nt) * 16 + lm) * 256
                                                 + kt * 32 + lk];
                acc[nt] = __builtin_amdgcn_mfma_f32_16x16x32_bf16(av, bv, acc[nt], 0, 0, 0);
            }
        }
#pragma unroll
        for (int nt = 0; nt < 4; ++nt) {
            int col = (ng0 + nt) * 16 + lm;
            float bb = b2[col];
#pragma unroll
            for (int j = 0; j < 4; ++j) {
                int rl = m * 16 + lr + j;
                out[(size_t)(row0 + rl) * 128 + col] = Hs[rl][col] + acc[nt][j] + bb;
            }
        }
    }
}

extern "C" void kernel_launch(void* const* d_in, const int* in_sizes, int n_in,
                              void* d_out, int out_size, void* d_ws, size_t ws_size,
                              hipStream_t stream)
{
    const float* q  = (const float*)d_in[0];
    // d_in[1] = k : dead (per-node q·k dot is segment-constant, cancels in softmax)
    const float* v  = (const float*)d_in[2];
    const float* ef = (const float*)d_in[3];
    const float* H  = (const float*)d_in[4];
    // d_in[5] = Wq, d_in[6] = Wk : dead
    const float* Wv = (const float*)d_in[7];
    const float* We = (const float*)d_in[8];
    const float* be = (const float*)d_in[9];
    const float* Wo = (const float*)d_in[10];
    const float* W1 = (const float*)d_in[11];
    const float* b1 = (const float*)d_in[12];
    const float* W2 = (const float*)d_in[13];
    const float* b2 = (const float*)d_in[14];
    float* out = (float*)d_out;

    char* w = (char*)d_ws;
    auto carve = [&](size_t bytes) -> void* {
        void* p = (void*)w;
        w += (bytes + 255) & ~(size_t)255;
        return p;
    };
    int* edge_cnt   = (int*)carve(N_EDGES * 4);                    // zeroed (32 KB only)
    size_t zero_bytes = (size_t)(w - (char*)d_ws);
    int* node_cnt   = (int*)carve(N_NODES * 4);                    // plain-written by scan
    int* edge_nodes = (int*)carve((size_t)N_EDGES * MAXD * 4);
    int* node_edges = (int*)carve((size_t)N_NODES * NODE_CAP * 4);
    float* pe       = (float*)carve((size_t)N_NODES * 8 * 4);
    float* eexp     = (float*)carve((size_t)N_EDGES * 8 * 4);
    float* vsrc     = (float*)carve((size_t)N_NODES * 128 * 4);
    uint4* u4       = (uint4*)carve((size_t)N_NODES * 128 * 2);    // bf16
    uint4* msg4     = (uint4*)carve((size_t)N_EDGES * 128 * 2);    // bf16
    unsigned short* W1t = (unsigned short*)carve(32768 * 2);       // bf16 W1^T [256][128]
    unsigned short* W2t = (unsigned short*)carve(32768 * 2);       // bf16 W2^T [128][256]
    unsigned short* Wot = (unsigned short*)carve(16384 * 2);       // bf16 Wo^T [128][128]
    (void)ws_size; (void)in_sizes; (void)n_in; (void)out_size;

    hipMemsetAsync(d_ws, 0, zero_bytes, stream);

    scan_rows_k<<<N_NODES / 4, 256, 0, stream>>>(H, node_cnt, node_edges);
    vwe_k<<<GEMM_BLKS + PE_BLKS + CVT_BLKS, 256, 0, stream>>>(v, Wv, ef, We, Wo, W1, W2,
                                                              vsrc, pe, Wot, W1t, W2t);
    build_k<<<(N_NODES * NODE_CAP) / 256, 256, 0, stream>>>(node_cnt, node_edges,
                                                            edge_cnt, edge_nodes);
    eexp_k<<<(N_EDGES * 8) / 256, 256, 0, stream>>>(edge_cnt, edge_nodes, pe, be, eexp);
    zu_k<<<(N_NODES * 8) / 256, 256, 0, stream>>>(node_cnt, node_edges, eexp, vsrc, u4);
    msg_k<<<(N_EDGES * 16) / 256, 256, 0, stream>>>(edge_cnt, edge_nodes, eexp, u4, msg4);
    ffn_agg_k<<<N_NODES / 32, 256, 0, stream>>>(q, node_cnt, node_edges, msg4,
                                                Wot, W1t, b1, W2t, b2, out);
}